// Round 7
// baseline (592.308 us; speedup 1.0000x reference)
//
#include <hip/hip_runtime.h>
#include <math.h>

#define NEG_SLOPE 0.2f

constexpr int F_IN  = 128;
constexpr int HC1   = 256;  // H*HID
constexpr int HC2   = 160;  // H*CLS
constexpr int NHEAD = 4;

typedef _Float16 h8v __attribute__((ext_vector_type(8)));
typedef _Float16 h4v __attribute__((ext_vector_type(4)));
typedef float f4v __attribute__((ext_vector_type(4)));

// f32 += f16(lo/hi of packed) * f32 — single VOP3P instruction
#define FMIX_LO(acc, pk, wt) \
    asm("v_fma_mix_f32 %0, %1, %2, %0 op_sel:[0,0,0] op_sel_hi:[1,0,0]" \
        : "+v"(acc) : "v"(pk), "v"(wt))
#define FMIX_HI(acc, pk, wt) \
    asm("v_fma_mix_f32 %0, %1, %2, %0 op_sel:[1,0,0] op_sel_hi:[1,0,0]" \
        : "+v"(acc) : "v"(pk), "v"(wt))

__device__ __forceinline__ int edge_val(const void* p, int m64, long long i) {
    if (m64) return (int)((const long long*)p)[i];
    return ((const int*)p)[i];
}

// ---------------- init: zero stats+counts, block 0 detects edge dtype ----------------
__global__ void init_kernel(const unsigned int* __restrict__ ei_words, int* __restrict__ zbase,
                            int zcount, int* __restrict__ mode) {
    int gid = blockIdx.x * 256 + threadIdx.x;
    if (gid < zcount) zbase[gid] = 0;
    if (blockIdx.x == 0) {
        __shared__ unsigned int red[256];
        unsigned int v = 0;
        for (int i = 1 + 2 * (int)threadIdx.x; i < 4096; i += 512) v |= ei_words[i];
        red[threadIdx.x] = v;
        __syncthreads();
        for (int off = 128; off > 0; off >>= 1) {
            if (threadIdx.x < off) red[threadIdx.x] |= red[threadIdx.x + off];
            __syncthreads();
        }
        if (threadIdx.x == 0) *mode = (red[0] == 0u) ? 1 : 0;
    }
}

// ---------------- column stats (raw sums; finalize fused into standardize) ----------------
__global__ void colstats_kernel(const float* __restrict__ x, float* __restrict__ stats, int N) {
    int col = threadIdx.x & 127;
    int r0 = blockIdx.x * 256;
    int rend = min(r0 + 256, N);
    float s = 0.f, q = 0.f;
    for (int r = r0 + (int)(threadIdx.x >> 7); r < rend; r += 2) {
        float v = x[(long)r * F_IN + col];
        s += v;
        q += v * v;
    }
    __shared__ float sh[256];
    sh[threadIdx.x] = s;
    __syncthreads();
    if (threadIdx.x < 128) atomicAdd(&stats[col], sh[threadIdx.x] + sh[threadIdx.x + 128]);
    __syncthreads();
    sh[threadIdx.x] = q;
    __syncthreads();
    if (threadIdx.x < 128) atomicAdd(&stats[128 + col], sh[threadIdx.x] + sh[threadIdx.x + 128]);
}

// standardize + fp16 convert; mean/inv-std computed inline from raw sums
__global__ void standardize_kernel(const float* __restrict__ x, const float* __restrict__ stats,
                                   _Float16* __restrict__ xs, int total4, float invN,
                                   float invN1) {
    int i = blockIdx.x * blockDim.x + threadIdx.x;
    if (i >= total4) return;
    int c = (i * 4) & (F_IN - 1);
    float4 s4 = *(const float4*)&stats[c];
    float4 q4 = *(const float4*)&stats[128 + c];
    float4 v = ((const float4*)x)[i];
    h4v o;
    o[0] = (_Float16)((v.x - s4.x * invN) / sqrtf((q4.x - s4.x * s4.x * invN) * invN1));
    o[1] = (_Float16)((v.y - s4.y * invN) / sqrtf((q4.y - s4.y * s4.y * invN) * invN1));
    o[2] = (_Float16)((v.z - s4.z * invN) / sqrtf((q4.z - s4.z * s4.z * invN) * invN1));
    o[3] = (_Float16)((v.w - s4.w * invN) / sqrtf((q4.w - s4.w * s4.w * invN) * invN1));
    ((h4v*)xs)[i] = o;
}

// ---------------- weights -> fp16 transposed, with att columns appended ----------------
__global__ void convert_w_kernel(const float* __restrict__ W1, const float* __restrict__ aS1,
                                 const float* __restrict__ aD1, _Float16* __restrict__ B1x,
                                 const float* __restrict__ W2, const float* __restrict__ aS2,
                                 const float* __restrict__ aD2, _Float16* __restrict__ B2x) {
    constexpr int T1 = (HC1 + 16) * F_IN;
    constexpr int T2 = (HC2 + 16) * HC1;
    int idx = blockIdx.x * blockDim.x + threadIdx.x;
    if (idx < T1) {
        int n = idx / F_IN, k = idx - n * F_IN;
        float v = 0.f;
        if (n < HC1) {
            v = W1[k * HC1 + n];
        } else {
            int n2 = n - HC1;
            if (n2 < 8) {
                int hd = n2 & 3;
                const float* a = (n2 < 4) ? aS1 : aD1;
                for (int c = 0; c < 64; c++) v += W1[k * HC1 + hd * 64 + c] * a[hd * 64 + c];
            }
        }
        B1x[n * F_IN + k] = (_Float16)v;
    } else if (idx < T1 + T2) {
        int i2 = idx - T1;
        int n = i2 / HC1, k = i2 - n * HC1;
        float v = 0.f;
        if (n < HC2) {
            v = W2[k * HC2 + n];
        } else {
            int n2 = n - HC2;
            if (n2 < 8) {
                int hd = n2 & 3;
                const float* a = (n2 < 4) ? aS2 : aD2;
                for (int c = 0; c < 40; c++) v += W2[k * HC2 + hd * 40 + c] * a[hd * 40 + c];
            }
        }
        B2x[n * HC1 + k] = (_Float16)v;
    }
}

// ---------------- MFMA f16 GEMM with fused attention scores ----------------
// C is written in SLICE-MAJOR layout for the aggregate gather:
//   HC1: 8 regions of 32 ch: addr = (slice*M + row)*32 + (c&31), slice=c>>5
//   HC2: 8 regions of 20 ch: addr = (slice*M + row)*20 + off,   slice=c/20
template <int Nc, int K>
__global__ __launch_bounds__(256) void gemm_att_kernel(const _Float16* __restrict__ A,
                                                       const _Float16* __restrict__ Btx,
                                                       _Float16* __restrict__ C_,
                                                       float* __restrict__ as_,
                                                       float* __restrict__ ad_, int M) {
    constexpr int NT = Nc / 16;
    constexpr int NTT = NT + 1;
    constexpr int KT = K / 32;
    int w = threadIdx.x >> 6;
    int l = threadIdx.x & 63;
    int quad = l >> 4, lan = l & 15;
    int row = blockIdx.x * 64 + w * 16 + lan;
    int arow = min(row, M - 1);
    f4v acc[NTT] = {};
    const _Float16* Aptr = A + (long)arow * K + quad * 8;
#pragma unroll
    for (int k0 = 0; k0 < KT; k0++) {
        h8v af = *(const h8v*)(Aptr + k0 * 32);
#pragma unroll
        for (int ct = 0; ct < NTT; ct++) {
            const _Float16* Bptr = Btx + (long)(ct * 16 + lan) * K + k0 * 32 + quad * 8;
            h8v bf = *(const h8v*)Bptr;
            acc[ct] = __builtin_amdgcn_mfma_f32_16x16x32_f16(af, bf, acc[ct], 0, 0, 0);
        }
    }
    int orow = blockIdx.x * 64 + w * 16 + quad * 4;
#pragma unroll
    for (int r = 0; r < 4; r++) {
        int gr = orow + r;
        if (gr < M) {
#pragma unroll
            for (int ct = 0; ct < NT; ct++) {
                int c = ct * 16 + lan;
                if (Nc == 256) {
                    int slice = c >> 5, off = c & 31;
                    C_[((size_t)slice * M + gr) * 32 + off] = (_Float16)acc[ct][r];
                } else {
                    int slice = (c * 205) >> 12;  // c/20 for c<160
                    int off = c - slice * 20;
                    C_[((size_t)slice * M + gr) * 20 + off] = (_Float16)acc[ct][r];
                }
            }
            float av = acc[NT][r];
            if (lan < 4)
                as_[gr * 4 + lan] = av;
            else if (lan < 8)
                ad_[gr * 4 + lan - 4] = av;
        }
    }
}

// ---------------- CSR build over dst ----------------
__global__ void count_kernel(const void* __restrict__ ei, const int* __restrict__ mode, int E,
                             int* __restrict__ counts, int* __restrict__ pos) {
    int e = blockIdx.x * blockDim.x + threadIdx.x;
    if (e >= E) return;
    int d = edge_val(ei, *mode, (long long)E + e);
    pos[e] = atomicAdd(&counts[d], 1);
}

__global__ void scan_block_kernel(const int* __restrict__ counts, int* __restrict__ offsets,
                                  int* __restrict__ blocksum, int N) {
    int t = threadIdx.x;
    int i = blockIdx.x * 256 + t;
    int v = (i < N) ? counts[i] + 1 : 0;
    int lane = t & 63, w = t >> 6;
    int x = v;
#pragma unroll
    for (int d = 1; d < 64; d <<= 1) {
        int y = __shfl_up(x, d);
        if (lane >= d) x += y;
    }
    __shared__ int wsum[4];
    if (lane == 63) wsum[w] = x;
    __syncthreads();
    int base = 0;
    for (int k = 0; k < w; k++) base += wsum[k];
    int incl = x + base;
    if (i < N) offsets[i + 1] = incl;
    if (t == 255) blocksum[blockIdx.x] = incl;
}

__global__ void scan_add_kernel(const int* __restrict__ blocksum, int* __restrict__ offsets, int N,
                                int nb) {
    int t = threadIdx.x;
    int v = (t < nb) ? blocksum[t] : 0;
    int lane = t & 63, w = t >> 6;
    int x = v;
#pragma unroll
    for (int d = 1; d < 64; d <<= 1) {
        int y = __shfl_up(x, d);
        if (lane >= d) x += y;
    }
    __shared__ int wsum[4];
    __shared__ int excl[256];
    if (lane == 63) wsum[w] = x;
    __syncthreads();
    int base = 0;
    for (int k = 0; k < w; k++) base += wsum[k];
    excl[t] = x + base - v;
    __syncthreads();
    int myb = excl[blockIdx.x];
    int i = blockIdx.x * 256 + t;
    if (i < N) offsets[i + 1] += myb;
    if (i == 0) offsets[0] = 0;
}

__global__ void fill_csr_kernel(const void* __restrict__ ei, const int* __restrict__ mode, int E,
                                int N, const int* __restrict__ offsets,
                                const int* __restrict__ pos, int* __restrict__ csr) {
    int e = blockIdx.x * blockDim.x + threadIdx.x;
    if (e < E) {
        int m = *mode;
        int s = edge_val(ei, m, e);
        int d = edge_val(ei, m, (long long)E + e);
        csr[offsets[d] + 1 + pos[e]] = s;
    } else if (e < E + N) {
        int n = e - E;
        csr[offsets[n]] = n;
    }
}

// ---------------- softmax + aggregation: XCD channel-sliced gather ----------------
// Block = one (4-node group, channel slice). slice = blockIdx&7 pins each slice
// region to one XCD under round-robin dispatch; slice region (3.2/2 MB) is
// L2-resident there. Wave: 8 edges x 8 lanes x 4ch. A 32/20-ch slice lies in a
// single head, so phase 1 stages one exp weight per edge. Zero barriers.
template <int HC, bool RELU, typename OutT>
__global__ __launch_bounds__(256) void aggregate_kernel(
    const _Float16* __restrict__ hbs, const float* __restrict__ a_src,
    const float* __restrict__ a_dst, const int* __restrict__ offsets,
    const int* __restrict__ csr_src, const float* __restrict__ bias, OutT* __restrict__ out,
    int Ntot) {
    constexpr int SLICE_CH = (HC == 256) ? 32 : 20;  // channels per slice
    constexpr int RS = SLICE_CH * 2;                 // slice-row bytes
    constexpr int ACT_SUB = SLICE_CH / 4;            // active csub lanes (8 or 5)
    int w = threadIdx.x >> 6, l = threadIdx.x & 63;
    int slice = blockIdx.x & 7;
    int node = (blockIdx.x >> 3) * 4 + w;
    if (node >= Ntot) return;  // wave-uniform exit
    int head = slice >> 1;
    int e_sub = l >> 3, csub = l & 7;
    bool lane_on = csub < ACT_SUB;

    __shared__ int sidx_sh[4][64];
    __shared__ float ew_sh[4][64];

    int start = offsets[node], end = offsets[node + 1];
    int deg = end - start;
    float adh = a_dst[node * 4 + head];
    const char* sbase = (const char*)hbs + (size_t)slice * Ntot * RS + csub * 8;

    float ds = 0.f;
    float a0 = 0.f, a1 = 0.f, a2 = 0.f, a3 = 0.f;

    for (int base = 0; base < deg; base += 64) {
        int cnt = min(64, deg - base);
        if (l < cnt) {
            int s = csr_src[start + base + l];
            sidx_sh[w][l] = s * RS;
            float e = a_src[s * 4 + head] + adh;
            e = fmaxf(e, NEG_SLOPE * e);
            float we = __expf(e);
            ew_sh[w][l] = we;
            ds += we;
        }
        for (int j = 0; j < cnt; j += 8) {
            int myj = j + e_sub;
            if (lane_on && myj < cnt) {
                int off = sidx_sh[w][myj];
                float wt = ew_sh[w][myj];
                int2 p = *(const int2*)(sbase + off);
                FMIX_LO(a0, p.x, wt);
                FMIX_HI(a1, p.x, wt);
                FMIX_LO(a2, p.y, wt);
                FMIX_HI(a3, p.y, wt);
            }
        }
    }

    // softmax denominator for this head (lanes >= cnt contributed 0)
#pragma unroll
    for (int off = 1; off < 64; off <<= 1) ds += __shfl_xor(ds, off);
    // sum channel accumulators across the 8 e_sub groups (stride-8 lanes)
#pragma unroll
    for (int off = 8; off < 64; off <<= 1) {
        a0 += __shfl_xor(a0, off);
        a1 += __shfl_xor(a1, off);
        a2 += __shfl_xor(a2, off);
        a3 += __shfl_xor(a3, off);
    }

    if (e_sub == 0 && lane_on) {
        float inv = 1.0f / ds;
        float4 bv = *(const float4*)&bias[slice * SLICE_CH + csub * 4];
        float r0 = a0 * inv + bv.x;
        float r1 = a1 * inv + bv.y;
        float r2 = a2 * inv + bv.z;
        float r3 = a3 * inv + bv.w;
        if (RELU) {
            r0 = fmaxf(r0, 0.f);
            r1 = fmaxf(r1, 0.f);
            r2 = fmaxf(r2, 0.f);
            r3 = fmaxf(r3, 0.f);
        }
        OutT* op = out + (size_t)node * HC + slice * SLICE_CH + csub * 4;
        if (sizeof(OutT) == 2) {
            h4v hv;
            hv[0] = (_Float16)r0;
            hv[1] = (_Float16)r1;
            hv[2] = (_Float16)r2;
            hv[3] = (_Float16)r3;
            *(h4v*)op = hv;
        } else {
            *(float4*)op = make_float4(r0, r1, r2, r3);
        }
    }
}

// ---------------- launch ----------------
extern "C" void kernel_launch(void* const* d_in, const int* in_sizes, int n_in, void* d_out,
                              int out_size, void* d_ws, size_t ws_size, hipStream_t stream) {
    const float* x = (const float*)d_in[0];
    const void* ei = d_in[1];
    const float* W1 = (const float*)d_in[2];
    const float* attS1 = (const float*)d_in[3];
    const float* attD1 = (const float*)d_in[4];
    const float* b1 = (const float*)d_in[5];
    const float* W2 = (const float*)d_in[6];
    const float* attS2 = (const float*)d_in[7];
    const float* attD2 = (const float*)d_in[8];
    const float* b2 = (const float*)d_in[9];
    float* out = (float*)d_out;

    int N = in_sizes[0] / F_IN;  // 50000
    int E = in_sizes[1] / 2;     // 800000
    int nb = (N + 255) / 256;
    int nagg = ((N + 3) / 4) * 8;  // slice-parallel aggregate grid

    _Float16* xs_h = (_Float16*)d_ws;             // N*128
    _Float16* hb1 = xs_h + (size_t)N * F_IN;      // N*256 (slice-major, 8 x N x 32ch)
    _Float16* o1h = hb1 + (size_t)N * HC1;        // N*256 (standard row-major)
    _Float16* hb2 = o1h + (size_t)N * HC1;        // N*160 (slice-major, 8 x N x 20ch)
    _Float16* B1x = hb2 + (size_t)N * HC2;        // 272*128
    _Float16* B2x = B1x + (HC1 + 16) * F_IN;      // 176*256
    float* as1 = (float*)(B2x + (HC2 + 16) * HC1);
    float* ad1 = as1 + (size_t)N * NHEAD;
    float* as2 = ad1 + (size_t)N * NHEAD;
    float* ad2 = as2 + (size_t)N * NHEAD;
    float* stats = ad2 + (size_t)N * NHEAD;       // 256
    int* counts = (int*)(stats + 256);            // N (zeroed with stats)
    int* offsets = counts + N;                    // N+1 (pad 4)
    int* csr = offsets + (N + 4);                 // E+N
    int* blocksum = csr + (E + N);                // 256
    int* mode = blocksum + 256;                   // 1
    int* pos = (int*)hb2;  // E ints; dead before gemm2 writes hb2

    init_kernel<<<(N + 256 + 255) / 256, 256, 0, stream>>>((const unsigned int*)ei, (int*)stats,
                                                           256 + N, mode);
    colstats_kernel<<<nb, 256, 0, stream>>>(x, stats, N);
    int total4 = N * F_IN / 4;
    standardize_kernel<<<(total4 + 255) / 256, 256, 0, stream>>>(
        x, stats, xs_h, total4, 1.0f / (float)N, 1.0f / (float)(N - 1));
    constexpr int TCV = (HC1 + 16) * F_IN + (HC2 + 16) * HC1;
    convert_w_kernel<<<(TCV + 255) / 256, 256, 0, stream>>>(W1, attS1, attD1, B1x, W2, attS2,
                                                            attD2, B2x);
    count_kernel<<<(E + 255) / 256, 256, 0, stream>>>(ei, mode, E, counts, pos);
    scan_block_kernel<<<nb, 256, 0, stream>>>(counts, offsets, blocksum, N);
    scan_add_kernel<<<nb, 256, 0, stream>>>(blocksum, offsets, N, nb);
    fill_csr_kernel<<<(E + N + 255) / 256, 256, 0, stream>>>(ei, mode, E, N, offsets, pos, csr);

    gemm_att_kernel<HC1, F_IN>
        <<<(N + 63) / 64, 256, 0, stream>>>(xs_h, B1x, hb1, as1, ad1, N);
    aggregate_kernel<HC1, true, _Float16>
        <<<nagg, 256, 0, stream>>>(hb1, as1, ad1, offsets, csr, b1, o1h, N);

    gemm_att_kernel<HC2, HC1>
        <<<(N + 63) / 64, 256, 0, stream>>>(o1h, B2x, hb2, as2, ad2, N);
    aggregate_kernel<HC2, false, float>
        <<<nagg, 256, 0, stream>>>(hb2, as2, ad2, offsets, csr, b2, out, N);
}

// Round 8
// 396.640 us; speedup vs baseline: 1.4933x; 1.4933x over previous
//
#include <hip/hip_runtime.h>
#include <math.h>

#define NEG_SLOPE 0.2f

constexpr int F_IN  = 128;
constexpr int HC1   = 256;  // H*HID
constexpr int HC2   = 160;  // H*CLS
constexpr int NHEAD = 4;

typedef _Float16 h8v __attribute__((ext_vector_type(8)));
typedef _Float16 h4v __attribute__((ext_vector_type(4)));
typedef float f4v __attribute__((ext_vector_type(4)));

// f32 += f16(lo/hi of packed) * f32 — single VOP3P instruction
#define FMIX_LO(acc, pk, wt) \
    asm("v_fma_mix_f32 %0, %1, %2, %0 op_sel:[0,0,0] op_sel_hi:[1,0,0]" \
        : "+v"(acc) : "v"(pk), "v"(wt))
#define FMIX_HI(acc, pk, wt) \
    asm("v_fma_mix_f32 %0, %1, %2, %0 op_sel:[1,0,0] op_sel_hi:[1,0,0]" \
        : "+v"(acc) : "v"(pk), "v"(wt))

__device__ __forceinline__ int edge_val(const void* p, int m64, long long i) {
    if (m64) return (int)((const long long*)p)[i];
    return ((const int*)p)[i];
}

// ---------------- dispatch 2: edge dtype detect ----------------
__global__ void detect_kernel(const unsigned int* __restrict__ ei_words, int* __restrict__ mode) {
    __shared__ unsigned int red[256];
    unsigned int v = 0;
    for (int i = 1 + 2 * (int)threadIdx.x; i < 4096; i += 512) v |= ei_words[i];
    red[threadIdx.x] = v;
    __syncthreads();
    for (int off = 128; off > 0; off >>= 1) {
        if (threadIdx.x < off) red[threadIdx.x] |= red[threadIdx.x + off];
        __syncthreads();
    }
    if (threadIdx.x == 0) *mode = (red[0] == 0u) ? 1 : 0;
}

// ---------------- dispatch 3 (fused): count | colstats | convert_w ----------------
__global__ __launch_bounds__(256) void fused_pre_kernel(
    const void* __restrict__ ei, const int* __restrict__ mode, int E, int* __restrict__ counts,
    int* __restrict__ pos, const float* __restrict__ x, float* __restrict__ stats, int N,
    const float* __restrict__ W1, const float* __restrict__ aS1, const float* __restrict__ aD1,
    _Float16* __restrict__ B1x, const float* __restrict__ W2, const float* __restrict__ aS2,
    const float* __restrict__ aD2, _Float16* __restrict__ B2x, int nbCnt, int nbStats) {
    int b = blockIdx.x;
    if (b < nbCnt) {
        // ---- count: pos[e] = rank of edge within its dst ----
        int e = b * 256 + (int)threadIdx.x;
        if (e < E) {
            int d = edge_val(ei, *mode, (long long)E + e);
            pos[e] = atomicAdd(&counts[d], 1);
        }
    } else if (b < nbCnt + nbStats) {
        // ---- colstats: raw per-column sum / sumsq ----
        int col = threadIdx.x & 127;
        int r0 = (b - nbCnt) * 256;
        int rend = min(r0 + 256, N);
        float s = 0.f, q = 0.f;
        for (int r = r0 + (int)(threadIdx.x >> 7); r < rend; r += 2) {
            float v = x[(long)r * F_IN + col];
            s += v;
            q += v * v;
        }
        __shared__ float sh[256];
        sh[threadIdx.x] = s;
        __syncthreads();
        if (threadIdx.x < 128) atomicAdd(&stats[col], sh[threadIdx.x] + sh[threadIdx.x + 128]);
        __syncthreads();
        sh[threadIdx.x] = q;
        __syncthreads();
        if (threadIdx.x < 128)
            atomicAdd(&stats[128 + col], sh[threadIdx.x] + sh[threadIdx.x + 128]);
    } else {
        // ---- convert weights -> fp16 transposed + att columns ----
        constexpr int T1 = (HC1 + 16) * F_IN;
        constexpr int T2 = (HC2 + 16) * HC1;
        int idx = (b - nbCnt - nbStats) * 256 + (int)threadIdx.x;
        if (idx < T1) {
            int n = idx / F_IN, k = idx - n * F_IN;
            float v = 0.f;
            if (n < HC1) {
                v = W1[k * HC1 + n];
            } else {
                int n2 = n - HC1;
                if (n2 < 8) {
                    int hd = n2 & 3;
                    const float* a = (n2 < 4) ? aS1 : aD1;
                    for (int c = 0; c < 64; c++) v += W1[k * HC1 + hd * 64 + c] * a[hd * 64 + c];
                }
            }
            B1x[n * F_IN + k] = (_Float16)v;
        } else if (idx < T1 + T2) {
            int i2 = idx - T1;
            int n = i2 / HC1, k = i2 - n * HC1;
            float v = 0.f;
            if (n < HC2) {
                v = W2[k * HC2 + n];
            } else {
                int n2 = n - HC2;
                if (n2 < 8) {
                    int hd = n2 & 3;
                    const float* a = (n2 < 4) ? aS2 : aD2;
                    for (int c = 0; c < 40; c++) v += W2[k * HC2 + hd * 40 + c] * a[hd * 40 + c];
                }
            }
            B2x[n * HC1 + k] = (_Float16)v;
        }
    }
}

// ---------------- dispatch 4 (fused): standardize | scan_block ----------------
__global__ __launch_bounds__(256) void fused_mid_kernel(
    const float* __restrict__ x, const float* __restrict__ stats, _Float16* __restrict__ xs,
    int total4, float invN, float invN1, const int* __restrict__ counts,
    int* __restrict__ offsets, int* __restrict__ blocksum, int N, int nbStd) {
    int b = blockIdx.x;
    if (b < nbStd) {
        int i = b * 256 + (int)threadIdx.x;
        if (i >= total4) return;
        int c = (i * 4) & (F_IN - 1);
        float4 s4 = *(const float4*)&stats[c];
        float4 q4 = *(const float4*)&stats[128 + c];
        float4 v = ((const float4*)x)[i];
        h4v o;
        o[0] = (_Float16)((v.x - s4.x * invN) / sqrtf((q4.x - s4.x * s4.x * invN) * invN1));
        o[1] = (_Float16)((v.y - s4.y * invN) / sqrtf((q4.y - s4.y * s4.y * invN) * invN1));
        o[2] = (_Float16)((v.z - s4.z * invN) / sqrtf((q4.z - s4.z * s4.z * invN) * invN1));
        o[3] = (_Float16)((v.w - s4.w * invN) / sqrtf((q4.w - s4.w * s4.w * invN) * invN1));
        ((h4v*)xs)[i] = o;
    } else {
        // scan_block: local inclusive prefix of counts+1 (self-loop folded in)
        int t = threadIdx.x;
        int i = (b - nbStd) * 256 + t;
        int v = (i < N) ? counts[i] + 1 : 0;
        int lane = t & 63, w = t >> 6;
        int xv = v;
#pragma unroll
        for (int d = 1; d < 64; d <<= 1) {
            int y = __shfl_up(xv, d);
            if (lane >= d) xv += y;
        }
        __shared__ int wsum[4];
        if (lane == 63) wsum[w] = xv;
        __syncthreads();
        int base = 0;
        for (int k = 0; k < w; k++) base += wsum[k];
        int incl = xv + base;
        if (i < N) offsets[i + 1] = incl;
        if (t == 255) blocksum[b - nbStd] = incl;
    }
}

// ---------------- dispatch 5: scan_add ----------------
__global__ void scan_add_kernel(const int* __restrict__ blocksum, int* __restrict__ offsets, int N,
                                int nb) {
    int t = threadIdx.x;
    int v = (t < nb) ? blocksum[t] : 0;
    int lane = t & 63, w = t >> 6;
    int x = v;
#pragma unroll
    for (int d = 1; d < 64; d <<= 1) {
        int y = __shfl_up(x, d);
        if (lane >= d) x += y;
    }
    __shared__ int wsum[4];
    __shared__ int excl[256];
    if (lane == 63) wsum[w] = x;
    __syncthreads();
    int base = 0;
    for (int k = 0; k < w; k++) base += wsum[k];
    excl[t] = x + base - v;
    __syncthreads();
    int myb = excl[blockIdx.x];
    int i = blockIdx.x * 256 + t;
    if (i < N) offsets[i + 1] += myb;
    if (i == 0) offsets[0] = 0;
}

// ---------------- MFMA f16 GEMM body (row-major C + fused att scores) ----------------
template <int Nc, int K>
__device__ __forceinline__ void gemm_att_body(int blk, const _Float16* __restrict__ A,
                                              const _Float16* __restrict__ Btx,
                                              _Float16* __restrict__ C_, float* __restrict__ as_,
                                              float* __restrict__ ad_, int M) {
    constexpr int NT = Nc / 16;
    constexpr int NTT = NT + 1;
    constexpr int KT = K / 32;
    int w = threadIdx.x >> 6;
    int l = threadIdx.x & 63;
    int quad = l >> 4, lan = l & 15;
    int row = blk * 64 + w * 16 + lan;
    int arow = min(row, M - 1);
    f4v acc[NTT] = {};
    const _Float16* Aptr = A + (long)arow * K + quad * 8;
#pragma unroll
    for (int k0 = 0; k0 < KT; k0++) {
        h8v af = *(const h8v*)(Aptr + k0 * 32);
#pragma unroll
        for (int ct = 0; ct < NTT; ct++) {
            const _Float16* Bptr = Btx + (long)(ct * 16 + lan) * K + k0 * 32 + quad * 8;
            h8v bf = *(const h8v*)Bptr;
            acc[ct] = __builtin_amdgcn_mfma_f32_16x16x32_f16(af, bf, acc[ct], 0, 0, 0);
        }
    }
    int orow = blk * 64 + w * 16 + quad * 4;
#pragma unroll
    for (int r = 0; r < 4; r++) {
        int gr = orow + r;
        if (gr < M) {
            _Float16* out = C_ + (long)gr * Nc + lan;
#pragma unroll
            for (int ct = 0; ct < NT; ct++) out[ct * 16] = (_Float16)acc[ct][r];
            float av = acc[NT][r];
            if (lan < 4)
                as_[gr * 4 + lan] = av;
            else if (lan < 8)
                ad_[gr * 4 + lan - 4] = av;
        }
    }
}

// ---------------- dispatch 6 (fused): fill_csr | gemm1 ----------------
__global__ __launch_bounds__(256) void fused_fill_g1_kernel(
    const void* __restrict__ ei, const int* __restrict__ mode, int E, int N,
    const int* __restrict__ offsets, const int* __restrict__ pos, int* __restrict__ csr,
    int nbFill, const _Float16* __restrict__ A, const _Float16* __restrict__ B1x,
    _Float16* __restrict__ C_, float* __restrict__ as_, float* __restrict__ ad_) {
    int b = blockIdx.x;
    if (b < nbFill) {
        int e = b * 256 + (int)threadIdx.x;
        if (e < E) {
            int m = *mode;
            int s = edge_val(ei, m, e);
            int d = edge_val(ei, m, (long long)E + e);
            csr[offsets[d] + 1 + pos[e]] = s;
        } else if (e < E + N) {
            int n = e - E;
            csr[offsets[n]] = n;
        }
    } else {
        gemm_att_body<HC1, F_IN>(b - nbFill, A, B1x, C_, as_, ad_, N);
    }
}

// ---------------- dispatch 8: gemm2 ----------------
__global__ __launch_bounds__(256) void gemm2_kernel(const _Float16* __restrict__ A,
                                                    const _Float16* __restrict__ B2x,
                                                    _Float16* __restrict__ C_,
                                                    float* __restrict__ as_,
                                                    float* __restrict__ ad_, int M) {
    gemm_att_body<HC2, HC1>(blockIdx.x, A, B2x, C_, as_, ad_, M);
}

// ---------------- aggregates (R6 row-major structure, x8 unroll) ----------------
template <int HC, bool RELU, typename OutT>
__global__ __launch_bounds__(256) void aggregate_kernel(
    const _Float16* __restrict__ hb, const float* __restrict__ a_src,
    const float* __restrict__ a_dst, const int* __restrict__ offsets,
    const int* __restrict__ csr_src, const float* __restrict__ bias, OutT* __restrict__ out,
    int Ntot) {
    constexpr int ACT = HC / 4;       // active gather lanes (64 or 40)
    constexpr int CHPH = HC / NHEAD;  // channels per head
    constexpr bool FULL = (ACT == 64);
    int w = threadIdx.x >> 6, l = threadIdx.x & 63;
    int node = blockIdx.x * 4 + w;
    if (node >= Ntot) return;  // wave-uniform exit

    __shared__ __align__(16) int sidx_sh[4][64];     // byte offsets into hb
    __shared__ __align__(16) float ew_sh[4][64][4];  // per-edge per-head exp weights

    int start = offsets[node], end = offsets[node + 1];
    int deg = end - start;
    float4 adv = ((const float4*)a_dst)[node];
    const int hd = min((4 * l) / CHPH, 3);
    const char* hbl = (const char*)hb + 8 * l;  // this lane's 4-channel slice

    float ds0 = 0.f, ds1 = 0.f, ds2 = 0.f, ds3 = 0.f;
    float a0 = 0.f, a1 = 0.f, a2 = 0.f, a3 = 0.f;

    for (int base = 0; base < deg; base += 64) {
        int cnt = min(64, deg - base);
        if (l < cnt) {
            int s = csr_src[start + base + l];
            sidx_sh[w][l] = s * (HC * 2);
            float4 av = ((const float4*)a_src)[s];
            float e0 = av.x + adv.x, e1 = av.y + adv.y, e2 = av.z + adv.z, e3 = av.w + adv.w;
            e0 = fmaxf(e0, NEG_SLOPE * e0);
            e1 = fmaxf(e1, NEG_SLOPE * e1);
            e2 = fmaxf(e2, NEG_SLOPE * e2);
            e3 = fmaxf(e3, NEG_SLOPE * e3);
            float w0 = __expf(e0), w1 = __expf(e1), w2 = __expf(e2), w3 = __expf(e3);
            *(float4*)ew_sh[w][l] = make_float4(w0, w1, w2, w3);
            ds0 += w0;
            ds1 += w1;
            ds2 += w2;
            ds3 += w3;
        }
        int j = 0;
        for (; j + 7 < cnt; j += 8) {
            int4 oa = *(const int4*)&sidx_sh[w][j];
            int4 ob = *(const int4*)&sidx_sh[w][j + 4];
            float w0 = ew_sh[w][j + 0][hd], w1 = ew_sh[w][j + 1][hd];
            float w2 = ew_sh[w][j + 2][hd], w3 = ew_sh[w][j + 3][hd];
            float w4 = ew_sh[w][j + 4][hd], w5 = ew_sh[w][j + 5][hd];
            float w6 = ew_sh[w][j + 6][hd], w7 = ew_sh[w][j + 7][hd];
            if (FULL || l < ACT) {
                int2 p0 = *(const int2*)(hbl + oa.x);
                int2 p1 = *(const int2*)(hbl + oa.y);
                int2 p2 = *(const int2*)(hbl + oa.z);
                int2 p3 = *(const int2*)(hbl + oa.w);
                int2 p4 = *(const int2*)(hbl + ob.x);
                int2 p5 = *(const int2*)(hbl + ob.y);
                int2 p6 = *(const int2*)(hbl + ob.z);
                int2 p7 = *(const int2*)(hbl + ob.w);
                FMIX_LO(a0, p0.x, w0); FMIX_HI(a1, p0.x, w0);
                FMIX_LO(a2, p0.y, w0); FMIX_HI(a3, p0.y, w0);
                FMIX_LO(a0, p1.x, w1); FMIX_HI(a1, p1.x, w1);
                FMIX_LO(a2, p1.y, w1); FMIX_HI(a3, p1.y, w1);
                FMIX_LO(a0, p2.x, w2); FMIX_HI(a1, p2.x, w2);
                FMIX_LO(a2, p2.y, w2); FMIX_HI(a3, p2.y, w2);
                FMIX_LO(a0, p3.x, w3); FMIX_HI(a1, p3.x, w3);
                FMIX_LO(a2, p3.y, w3); FMIX_HI(a3, p3.y, w3);
                FMIX_LO(a0, p4.x, w4); FMIX_HI(a1, p4.x, w4);
                FMIX_LO(a2, p4.y, w4); FMIX_HI(a3, p4.y, w4);
                FMIX_LO(a0, p5.x, w5); FMIX_HI(a1, p5.x, w5);
                FMIX_LO(a2, p5.y, w5); FMIX_HI(a3, p5.y, w5);
                FMIX_LO(a0, p6.x, w6); FMIX_HI(a1, p6.x, w6);
                FMIX_LO(a2, p6.y, w6); FMIX_HI(a3, p6.y, w6);
                FMIX_LO(a0, p7.x, w7); FMIX_HI(a1, p7.x, w7);
                FMIX_LO(a2, p7.y, w7); FMIX_HI(a3, p7.y, w7);
            }
        }
        for (; j + 3 < cnt; j += 4) {
            int4 o4 = *(const int4*)&sidx_sh[w][j];
            float w0 = ew_sh[w][j + 0][hd], w1 = ew_sh[w][j + 1][hd];
            float w2 = ew_sh[w][j + 2][hd], w3 = ew_sh[w][j + 3][hd];
            if (FULL || l < ACT) {
                int2 p0 = *(const int2*)(hbl + o4.x);
                int2 p1 = *(const int2*)(hbl + o4.y);
                int2 p2 = *(const int2*)(hbl + o4.z);
                int2 p3 = *(const int2*)(hbl + o4.w);
                FMIX_LO(a0, p0.x, w0); FMIX_HI(a1, p0.x, w0);
                FMIX_LO(a2, p0.y, w0); FMIX_HI(a3, p0.y, w0);
                FMIX_LO(a0, p1.x, w1); FMIX_HI(a1, p1.x, w1);
                FMIX_LO(a2, p1.y, w1); FMIX_HI(a3, p1.y, w1);
                FMIX_LO(a0, p2.x, w2); FMIX_HI(a1, p2.x, w2);
                FMIX_LO(a2, p2.y, w2); FMIX_HI(a3, p2.y, w2);
                FMIX_LO(a0, p3.x, w3); FMIX_HI(a1, p3.x, w3);
                FMIX_LO(a2, p3.y, w3); FMIX_HI(a3, p3.y, w3);
            }
        }
        for (; j < cnt; j++) {
            int off = sidx_sh[w][j];
            float w0 = ew_sh[w][j][hd];
            if (FULL || l < ACT) {
                int2 p0 = *(const int2*)(hbl + off);
                FMIX_LO(a0, p0.x, w0); FMIX_HI(a1, p0.x, w0);
                FMIX_LO(a2, p0.y, w0); FMIX_HI(a3, p0.y, w0);
            }
        }
    }

#pragma unroll
    for (int off = 1; off < 64; off <<= 1) {
        ds0 += __shfl_xor(ds0, off);
        ds1 += __shfl_xor(ds1, off);
        ds2 += __shfl_xor(ds2, off);
        ds3 += __shfl_xor(ds3, off);
    }

    if (FULL || l < ACT) {
        float dsel = hd == 0 ? ds0 : hd == 1 ? ds1 : hd == 2 ? ds2 : ds3;
        float inv = 1.0f / dsel;
        float4 bv = ((const float4*)bias)[l];
        float r0 = a0 * inv + bv.x;
        float r1 = a1 * inv + bv.y;
        float r2 = a2 * inv + bv.z;
        float r3 = a3 * inv + bv.w;
        if (RELU) {
            r0 = fmaxf(r0, 0.f);
            r1 = fmaxf(r1, 0.f);
            r2 = fmaxf(r2, 0.f);
            r3 = fmaxf(r3, 0.f);
        }
        OutT* op = out + (long)node * HC + 4 * l;
        if (sizeof(OutT) == 2) {
            h4v hv;
            hv[0] = (_Float16)r0;
            hv[1] = (_Float16)r1;
            hv[2] = (_Float16)r2;
            hv[3] = (_Float16)r3;
            *(h4v*)op = hv;
        } else {
            *(float4*)op = make_float4(r0, r1, r2, r3);
        }
    }
}

// ---------------- launch ----------------
extern "C" void kernel_launch(void* const* d_in, const int* in_sizes, int n_in, void* d_out,
                              int out_size, void* d_ws, size_t ws_size, hipStream_t stream) {
    const float* x = (const float*)d_in[0];
    const void* ei = d_in[1];
    const float* W1 = (const float*)d_in[2];
    const float* attS1 = (const float*)d_in[3];
    const float* attD1 = (const float*)d_in[4];
    const float* b1 = (const float*)d_in[5];
    const float* W2 = (const float*)d_in[6];
    const float* attS2 = (const float*)d_in[7];
    const float* attD2 = (const float*)d_in[8];
    const float* b2 = (const float*)d_in[9];
    float* out = (float*)d_out;

    int N = in_sizes[0] / F_IN;  // 50000
    int E = in_sizes[1] / 2;     // 800000
    int nb = (N + 255) / 256;    // 196
    int nw = (N + 3) / 4;        // wave-per-node aggregate grid

    _Float16* xs_h = (_Float16*)d_ws;             // N*128
    _Float16* hb1 = xs_h + (size_t)N * F_IN;      // N*256 row-major
    _Float16* o1h = hb1 + (size_t)N * HC1;        // N*256 row-major
    _Float16* hb2 = o1h + (size_t)N * HC1;        // N*160 (pos[] overlays this early)
    _Float16* B1x = hb2 + (size_t)N * HC2;        // 272*128
    _Float16* B2x = B1x + (HC1 + 16) * F_IN;      // 176*256
    float* as1 = (float*)(B2x + (HC2 + 16) * HC1);
    float* ad1 = as1 + (size_t)N * NHEAD;
    float* as2 = ad1 + (size_t)N * NHEAD;
    float* ad2 = as2 + (size_t)N * NHEAD;
    float* stats = ad2 + (size_t)N * NHEAD;       // 256
    int* counts = (int*)(stats + 256);            // N (zeroed with stats)
    int* offsets = counts + N;                    // N+1 (pad 4)
    int* csr = offsets + (N + 4);                 // E+N
    int* blocksum = csr + (E + N);                // 256
    int* mode = blocksum + 256;                   // 1
    int* pos = (int*)hb2;  // E ints; dead before gemm2 writes hb2

    int nbCnt = (E + 255) / 256;                         // 3125
    constexpr int TCV = (HC1 + 16) * F_IN + (HC2 + 16) * HC1;
    int nbConv = (TCV + 255) / 256;                      // 143
    int total4 = N * F_IN / 4;
    int nbStd = (total4 + 255) / 256;                    // 6250
    int nbFill = (E + N + 255) / 256;                    // 3321
    int nbG1 = (N + 63) / 64;                            // 782

    // 1. zero stats+counts (memset node)
    hipMemsetAsync(stats, 0, (256 + (size_t)N) * sizeof(int), stream);
    // 2. detect edge dtype
    detect_kernel<<<1, 256, 0, stream>>>((const unsigned int*)ei, mode);
    // 3. fused: count | colstats | convert_w
    fused_pre_kernel<<<nbCnt + nb + nbConv, 256, 0, stream>>>(
        ei, mode, E, counts, pos, x, stats, N, W1, attS1, attD1, B1x, W2, attS2, attD2, B2x,
        nbCnt, nb);
    // 4. fused: standardize | scan_block
    fused_mid_kernel<<<nbStd + nb, 256, 0, stream>>>(x, stats, xs_h, total4, 1.0f / (float)N,
                                                     1.0f / (float)(N - 1), counts, offsets,
                                                     blocksum, N, nbStd);
    // 5. scan_add
    scan_add_kernel<<<nb, 256, 0, stream>>>(blocksum, offsets, N, nb);
    // 6. fused: fill_csr | gemm1(+att)
    fused_fill_g1_kernel<<<nbFill + nbG1, 256, 0, stream>>>(ei, mode, E, N, offsets, pos, csr,
                                                            nbFill, xs_h, B1x, hb1, as1, ad1);
    // 7. aggregate layer 1
    aggregate_kernel<HC1, true, _Float16>
        <<<nw, 256, 0, stream>>>(hb1, as1, ad1, offsets, csr, b1, o1h, N);
    // 8. gemm2(+att)
    gemm2_kernel<<<nbG1, 256, 0, stream>>>(o1h, B2x, hb2, as2, ad2, N);
    // 9. aggregate layer 2
    aggregate_kernel<HC2, false, float>
        <<<nw, 256, 0, stream>>>(hb2, as2, ad2, offsets, csr, b2, out, N);
}